// Round 6
// baseline (45.593 us; speedup 1.0000x reference)
//
#include <hip/hip_runtime.h>

// Problem geometry (fixed by reference): B=16, L=2048, D=1024, fp32.
constexpr int L_CONST = 2048;
constexpr int D_CONST = 1024;
constexpr int NT      = 256;              // threads per block
constexpr int PER     = L_CONST / NT;     // 8 flags per thread
constexpr int ROWS    = 16;               // dest rows copied per block
constexpr int BATCH   = 8;                // rows loaded before storing (read depth)
constexpr int GROUPS  = L_CONST / ROWS;   // 128 blocks per batch row
constexpr int D4      = D_CONST / 4;      // 256 float4 per row

// Native clang vector (NOT HIP_vector_type) so __builtin_nontemporal_* accepts it.
typedef float floatx4 __attribute__((ext_vector_type(4)));

// Fused kernel: each block recomputes the stable-partition permutation for
// its batch row (flags L2-resident: 128 KB total), inverts it into LDS
// (dest -> src), then copies its ROWS dest rows. Phase 2 batches BATCH row
// loads into registers before storing (nt hint), keeping 8 x 16B reads in
// flight per thread so HBM read latency is hidden instead of being exposed
// on every load->store pair (R5 analysis: 45.4us vs ~32us traffic floor).
// NOTE (R5 lesson): only the nt HINT is safe; asm `sc0 sc1` LLC-bypass
// stores break coherence with the harness read-back -- do not retry.
__global__ __launch_bounds__(NT, 8) void fused_partition_gather(
    const float* __restrict__ in, const int* __restrict__ nl,
    float* __restrict__ out) {
    const int b = blockIdx.x / GROUPS;    // batch row
    const int g = blockIdx.x % GROUPS;    // dest-row group within batch row
    const int t = threadIdx.x;

    // --- Phase 1: per-row stable-partition scan (src -> dest), invert in LDS.
    const int4* row4 = (const int4*)(nl + (size_t)b * L_CONST);
    int4 v0 = row4[t * 2];
    int4 v1 = row4[t * 2 + 1];
    int flags[PER];
    flags[0] = (v0.x != 0); flags[1] = (v0.y != 0);
    flags[2] = (v0.z != 0); flags[3] = (v0.w != 0);
    flags[4] = (v1.x != 0); flags[5] = (v1.y != 0);
    flags[6] = (v1.z != 0); flags[7] = (v1.w != 0);
    int cnt = 0;
    #pragma unroll
    for (int k = 0; k < PER; ++k) cnt += flags[k];

    __shared__ int s[NT];
    __shared__ int lds_order[L_CONST];    // dest -> src, 8 KB
    s[t] = cnt;
    __syncthreads();
    #pragma unroll
    for (int off = 1; off < NT; off <<= 1) {
        int add = (t >= off) ? s[t - off] : 0;
        __syncthreads();
        s[t] += add;
        __syncthreads();
    }
    const int incl     = s[t];
    const int totalNon = s[NT - 1];
    const int exclNon  = incl - cnt;      // nonpads strictly before this span

    int run = 0;
    #pragma unroll
    for (int k = 0; k < PER; ++k) {
        const int j        = t * PER + k;            // source position
        const int npPrefix = exclNon + run;          // nonpads strictly before j
        const int dest = flags[k] ? npPrefix : (totalNon + (j - npPrefix));
        lds_order[dest] = j;                         // all dests distinct: no race
        run += flags[k];
    }
    __syncthreads();

    // --- Phase 2: copy ROWS dest rows in BATCH-deep load/store groups.
    const floatx4* inb  = (const floatx4*)in + (size_t)b * L_CONST * D4;
    floatx4*       outb = (floatx4*)out      + ((size_t)b * L_CONST + (size_t)g * ROWS) * D4;

    #pragma unroll
    for (int half = 0; half < ROWS / BATCH; ++half) {
        int srcs[BATCH];
        #pragma unroll
        for (int r = 0; r < BATCH; ++r)
            srcs[r] = lds_order[g * ROWS + half * BATCH + r];

        floatx4 v[BATCH];                  // 32 VGPRs of data in flight
        #pragma unroll
        for (int r = 0; r < BATCH; ++r)
            v[r] = inb[(size_t)srcs[r] * D4 + t];
        #pragma unroll
        for (int r = 0; r < BATCH; ++r)
            __builtin_nontemporal_store(v[r], &outb[(half * BATCH + r) * D4 + t]);
    }
}

extern "C" void kernel_launch(void* const* d_in, const int* in_sizes, int n_in,
                              void* d_out, int out_size, void* d_ws, size_t ws_size,
                              hipStream_t stream) {
    const float* sentout = (const float*)d_in[0];
    const int*   nl      = (const int*)d_in[1];
    float*       out     = (float*)d_out;

    const int B = in_sizes[1] / L_CONST;  // 16
    fused_partition_gather<<<B * GROUPS, NT, 0, stream>>>(sentout, nl, out);
}

// Round 7
// 43.767 us; speedup vs baseline: 1.0417x; 1.0417x over previous
//
#include <hip/hip_runtime.h>

// Problem geometry (fixed by reference): B=16, L=2048, D=1024, fp32.
constexpr int L_CONST = 2048;
constexpr int D_CONST = 1024;
constexpr int NT      = 256;              // threads per block
constexpr int PER     = L_CONST / NT;     // 8 flags per thread
constexpr int ROWS    = 16;               // SOURCE rows per block
constexpr int GROUPS  = L_CONST / ROWS;   // 128 blocks per batch row
constexpr int D4      = D_CONST / 4;      // 256 float4 per row

// Native clang vector (NOT HIP_vector_type) so nontemporal builtin accepts it.
typedef float floatx4 __attribute__((ext_vector_type(4)));

// Source-ordered fused kernel. Block g owns source rows [16g,16g+16): their
// LOAD addresses are known at entry (independent of the scan), so all 16 row
// loads are issued first and the flag scan runs UNDER their latency
// (sched_barrier pins the issue order). The stable partition sends a
// contiguous source span to two contiguous dest spans, so scatter stores
// stay near-contiguous. No LDS inverse table (R6 had 8 KB + extra barrier).
// NOTE (R5 lesson): only the `nt` HINT is safe for stores; asm sc0/sc1
// LLC-bypass broke harness read-back coherence -- do not retry.
__global__ __launch_bounds__(NT, 4) void fused_src_partition(
    const float* __restrict__ in, const int* __restrict__ nl,
    float* __restrict__ out) {
    const int b = blockIdx.x / GROUPS;    // batch row
    const int g = blockIdx.x % GROUPS;    // source-row group
    const int t = threadIdx.x;

    // --- Issue flag loads (scan needs them first)...
    const int4* row4 = (const int4*)(nl + (size_t)b * L_CONST);
    int4 f0 = row4[t * 2];
    int4 f1 = row4[t * 2 + 1];

    // --- ...then the 16 source-row data loads (64 KB contiguous per block).
    const floatx4* inb = (const floatx4*)in
                       + ((size_t)b * L_CONST + (size_t)g * ROWS) * D4;
    floatx4 v[ROWS];
    #pragma unroll
    for (int r = 0; r < ROWS; ++r) v[r] = inb[r * D4 + t];

    // Pin: everything above issues before anything below is scheduled.
    __builtin_amdgcn_sched_barrier(0);

    // --- Stable-partition scan over the full batch row (under load latency).
    int flags[PER];
    flags[0] = (f0.x != 0); flags[1] = (f0.y != 0);
    flags[2] = (f0.z != 0); flags[3] = (f0.w != 0);
    flags[4] = (f1.x != 0); flags[5] = (f1.y != 0);
    flags[6] = (f1.z != 0); flags[7] = (f1.w != 0);
    int cnt = 0;
    #pragma unroll
    for (int k = 0; k < PER; ++k) cnt += flags[k];

    __shared__ int s[NT];
    __shared__ int dstL[ROWS];            // dest row index for our 16 src rows
    s[t] = cnt;
    __syncthreads();
    #pragma unroll
    for (int off = 1; off < NT; off <<= 1) {
        int add = (t >= off) ? s[t - off] : 0;
        __syncthreads();
        s[t] += add;
        __syncthreads();
    }
    const int incl     = s[t];
    const int totalNon = s[NT - 1];
    const int exclNon  = incl - cnt;      // nonpads strictly before this span

    // Only the 2 threads owning positions [16g,16g+16) publish dest indices.
    const int j0 = g * ROWS;
    int run = 0;
    #pragma unroll
    for (int k = 0; k < PER; ++k) {
        const int j        = t * PER + k;            // source position
        const int npPrefix = exclNon + run;          // nonpads strictly before j
        if (j >= j0 && j < j0 + ROWS) {
            dstL[j - j0] = flags[k] ? npPrefix : (totalNon + (j - npPrefix));
        }
        run += flags[k];
    }
    __syncthreads();

    // --- Scatter stores: row r goes to dest row dstL[r] (LDS broadcast read).
    floatx4* outB = (floatx4*)out + (size_t)b * L_CONST * D4;
    #pragma unroll
    for (int r = 0; r < ROWS; ++r) {
        __builtin_nontemporal_store(v[r], outB + (size_t)dstL[r] * D4 + t);
    }
}

extern "C" void kernel_launch(void* const* d_in, const int* in_sizes, int n_in,
                              void* d_out, int out_size, void* d_ws, size_t ws_size,
                              hipStream_t stream) {
    const float* sentout = (const float*)d_in[0];
    const int*   nl      = (const int*)d_in[1];
    float*       out     = (float*)d_out;

    const int B = in_sizes[1] / L_CONST;  // 16
    fused_src_partition<<<B * GROUPS, NT, 0, stream>>>(sentout, nl, out);
}